// Round 1
// baseline (16197.247 us; speedup 1.0000x reference)
//
#include <hip/hip_runtime.h>
#include <hip/hip_cooperative_groups.h>

// Persistent cooperative LSTM kernel.
// Grid = 256 WGs x 128 threads (2 waves). WG id decode:
//   layer = wg>>7, dir = (wg>>6)&1, colblk = (wg>>1)&31 (8 h-cols), mhalf = wg&1 (32 batch rows)
// Superstep k: layer0 computes t=k, layer1 computes t=k-1  -> ONE grid sync per superstep.

typedef short v8s __attribute__((ext_vector_type(8)));
typedef float v4f __attribute__((ext_vector_type(4)));

#define S_LEN 512
#define BATCH 64
#define EMBD  300
#define XPAD  320
#define ROWP0 584   // 320 (x, padded) + 256 (h) + 8 pad  -> bank stride 4 mod 32 (2-way, free)
#define ROWP1 776   // 512 (x1) + 256 (h) + 8 pad

__device__ inline unsigned short f2bf(float x) {
  union { float f; unsigned u; } v; v.f = x;
  unsigned r = v.u + 0x7FFF + ((v.u >> 16) & 1);   // RNE
  return (unsigned short)(r >> 16);
}
__device__ inline float sigm(float x) { return 1.f / (1.f + __expf(-x)); }
__device__ inline float tanhf_(float x) {
  float e = __expf(-2.f * fabsf(x));
  float r = (1.f - e) / (1.f + e);
  return x >= 0.f ? r : -r;
}

// One step's dual-tile GEMM: acc0 = [i|f] tile, acc1 = [g|o] tile.
// All A fragments issued up-front (global, L2-hot) to hide latency; B from LDS.
template<int NK1, int NK2, int P2OFF>
__device__ inline void step_mm(const unsigned short* __restrict__ aP1,
                               const unsigned short* __restrict__ aP2,
                               const unsigned short* lds_t0,
                               const unsigned short* lds_t1,
                               v4f& acc0, v4f& acc1) {
  v8s a[NK1 + NK2];
#pragma unroll
  for (int i = 0; i < NK1; ++i) a[i] = *(const v8s*)(aP1 + i * 32);
#pragma unroll
  for (int i = 0; i < NK2; ++i) a[NK1 + i] = *(const v8s*)(aP2 + i * 32);
#pragma unroll
  for (int i = 0; i < NK1; ++i) {
    v8s b0 = *(const v8s*)(lds_t0 + i * 32);
    v8s b1 = *(const v8s*)(lds_t1 + i * 32);
    acc0 = __builtin_amdgcn_mfma_f32_16x16x32_bf16(a[i], b0, acc0, 0, 0, 0);
    acc1 = __builtin_amdgcn_mfma_f32_16x16x32_bf16(a[i], b1, acc1, 0, 0, 0);
  }
#pragma unroll
  for (int i = 0; i < NK2; ++i) {
    v8s b0 = *(const v8s*)(lds_t0 + P2OFF + i * 32);
    v8s b1 = *(const v8s*)(lds_t1 + P2OFF + i * 32);
    acc0 = __builtin_amdgcn_mfma_f32_16x16x32_bf16(a[NK1 + i], b0, acc0, 0, 0, 0);
    acc1 = __builtin_amdgcn_mfma_f32_16x16x32_bf16(a[NK1 + i], b1, acc1, 0, 0, 0);
  }
}

__global__ void __launch_bounds__(128, 1)
ContextAwareModel_9655086481739_kernel(
    const int* __restrict__ contexts, const int* __restrict__ positions,
    const float* __restrict__ emb,
    const float* __restrict__ wih0, const float* __restrict__ whh0,
    const float* __restrict__ bih0, const float* __restrict__ bhh0,
    const float* __restrict__ wih1, const float* __restrict__ whh1,
    const float* __restrict__ bih1, const float* __restrict__ bhh1,
    const float* __restrict__ wcls, const float* __restrict__ bcls,
    float* __restrict__ out, unsigned char* __restrict__ ws)
{
  __shared__ unsigned short smem[32 * ROWP1];   // 49,664 B

  const int wg   = blockIdx.x;
  const int tid  = threadIdx.x;
  const int layer  = wg >> 7;
  const int d      = (wg >> 6) & 1;
  const int colblk = (wg >> 1) & 31;
  const int mhalf  = wg & 1;
  const int wv   = tid >> 6;
  const int lane = tid & 63;
  const int quad = lane >> 4;
  const int lc   = lane & 15;
  const int hc0  = colblk * 8;
  const int hc   = hc0 + (lc & 7);
  const int m0   = mhalf * 32 + wv * 16;
  const int r_base = m0 + quad * 4;

  // workspace layout (bytes): Xbuf[512][64][320] bf16 | h0[2][64][512] bf16 |
  //                           h1[2][2][64][256] bf16 | tgt[64][512] f32
  unsigned short* Xbuf  = (unsigned short*)ws;
  unsigned short* h0buf = (unsigned short*)(ws + 20971520u);
  unsigned short* h1buf = (unsigned short*)(ws + 20971520u + 131072u);
  float*          tgt   = (float*)(ws + 20971520u + 262144u);

  const int ROWP = layer ? ROWP1 : ROWP0;

  // ---------------- stage 0 ----------------
  { // zero h-state (both parities, both layers; contiguous 131072 ushorts)
    for (int i = wg * 128 + tid; i < 131072; i += 256 * 128) h0buf[i] = 0;
  }
  { // embedding gather -> bf16, padded to 320
    int gw2 = wg * 2 + wv;                     // 0..511 waves
    for (int rl = 0; rl < 64; ++rl) {
      int rr = gw2 * 64 + rl;                  // rr = t*64 + b
      int t = rr >> 6, b = rr & 63;
      int tok = contexts[b * S_LEN + t];
      const float* erow = emb + (long)tok * EMBD;
#pragma unroll
      for (int i = 0; i < 5; ++i) {
        int kk = i * 64 + lane;
        float v = (kk < EMBD) ? erow[kk] : 0.f;
        if (kk < XPAD) Xbuf[rr * XPAD + kk] = f2bf(v);
      }
    }
  }
  { // weights -> LDS (bf16). Row lr: tile T=lr>>4, col c=lr&15, gate = T*2+(c>>3)
    const float* wih = layer ? wih1 : wih0;
    const float* whh = layer ? whh1 : whh0;
    const int KI  = layer ? 512 : 300;
    const int KIp = layer ? 512 : 320;
    const int KT  = layer ? 768 : 576;
    int lr = tid >> 2, sub = tid & 3;
    int c = lr & 15, T = lr >> 4;
    int gate = T * 2 + (c >> 3);
    int j = gate * 256 + hc0 + (c & 7);
    const float* wri = wih + (long)(d * 1024 + j) * KI;
    const float* wrh = whh + (long)(d * 1024 + j) * 256;
    for (int kk = sub; kk < ROWP; kk += 4) {
      float v = 0.f;
      if (kk < KI) v = wri[kk];
      else if (kk >= KIp && kk < KT) v = wrh[kk - KIp];
      smem[lr * ROWP + kk] = f2bf(v);
    }
  }
  float bias0, bias1;
  {
    const float* bi = layer ? bih1 : bih0;
    const float* bh = layer ? bhh1 : bhh0;
    int j0 = ((lc >> 3) & 1) * 256 + hc;        // gate i/f
    int j1 = (2 + ((lc >> 3) & 1)) * 256 + hc;  // gate g/o
    bias0 = bi[d * 1024 + j0] + bh[d * 1024 + j0];
    bias1 = bi[d * 1024 + j1] + bh[d * 1024 + j1];
  }
  int pos[4];
#pragma unroll
  for (int j = 0; j < 4; ++j) pos[j] = positions[r_base + j];

  float cst[4] = {0.f, 0.f, 0.f, 0.f};

  const unsigned short* lds_t0 = smem + lc * ROWP + quad * 8;
  const unsigned short* lds_t1 = smem + (16 + lc) * ROWP + quad * 8;

  cooperative_groups::grid_group gg = cooperative_groups::this_grid();
  __syncthreads();
  gg.sync();

  // ---------------- supersteps ----------------
  for (int k = 0; k <= S_LEN; ++k) {
    bool active = layer ? (k >= 1) : (k < S_LEN);
    if (active) {
      int t = layer ? (k - 1) : k;
      v4f acc0 = {bias0, bias0, bias0, bias0};
      v4f acc1 = {bias1, bias1, bias1, bias1};
      if (layer == 0) {
        // reads X_t and h0_{t-1} (parity (k-1)&1), writes h0_t (parity k&1)
        const unsigned short* aP1 = Xbuf + (t * BATCH + m0 + lc) * XPAD + quad * 8;
        const unsigned short* aP2 = h0buf + ((k + 1) & 1) * 32768 + (m0 + lc) * 512 + d * 256 + quad * 8;
        step_mm<10, 8, 320>(aP1, aP2, lds_t0, lds_t1, acc0, acc1);
      } else {
        // reads h0_t (parity t&1, written last superstep) and h1_{t-1}, writes h1_t
        const unsigned short* aP1 = h0buf + (t & 1) * 32768 + (m0 + lc) * 512 + quad * 8;
        const unsigned short* aP2 = h1buf + ((t + 1) & 1) * 32768 + d * 16384 + (m0 + lc) * 256 + quad * 8;
        step_mm<16, 8, 512>(aP1, aP2, lds_t0, lds_t1, acc0, acc1);
      }
      bool hi = (lc & 8) != 0;
#pragma unroll
      for (int j = 0; j < 4; ++j) {
        float a0 = acc0[j], a1 = acc1[j];
        float o0 = __shfl_xor(a0, 8);
        float o1 = __shfl_xor(a1, 8);
        float iv = hi ? o0 : a0;
        float fv = hi ? a0 : o0;
        float gv = hi ? o1 : a1;
        float ov = hi ? a1 : o1;
        float ii = sigm(iv), ff = sigm(fv), ggt = tanhf_(gv), oo = sigm(ov);
        float cn = ff * cst[j] + ii * ggt;
        cst[j] = cn;
        float hv = oo * tanhf_(cn);
        if (lc < 8) {   // lanes lc>=8 are duplicates after the shuffle
          unsigned short hb = f2bf(hv);
          int r = r_base + j;
          if (layer == 0) {
            h0buf[(k & 1) * 32768 + r * 512 + d * 256 + hc] = hb;
          } else {
            h1buf[(t & 1) * 32768 + d * 16384 + r * 256 + hc] = hb;
            if (pos[j] == t) tgt[r * 512 + d * 256 + hc] = hv;
          }
        }
      }
    }
    gg.sync();
  }

  // ---------------- epilogue ----------------
  {
    for (int i = wg * 128 + tid; i < BATCH * 512; i += 256 * 128) out[256 + i] = tgt[i];
    int gw = wg * 2 + wv;
    if (gw < 128) {                 // one wave per (b, class)
      int b = gw >> 1, cl = gw & 1;
      float s = 0.f;
#pragma unroll
      for (int i = 0; i < 8; ++i) {
        int j = i * 64 + lane;
        s += tgt[b * 512 + j] * wcls[cl * 512 + j];
      }
      s += __shfl_xor(s, 32); s += __shfl_xor(s, 16); s += __shfl_xor(s, 8);
      s += __shfl_xor(s, 4);  s += __shfl_xor(s, 2);  s += __shfl_xor(s, 1);
      if (lane == 0) {
        float L = s + bcls[cl];
        out[b * 2 + cl] = L;             // logits
        out[128 + b * 2 + cl] = sigm(L); // probs
      }
    }
  }
}

extern "C" void kernel_launch(void* const* d_in, const int* in_sizes, int n_in,
                              void* d_out, int out_size, void* d_ws, size_t ws_size,
                              hipStream_t stream) {
  (void)in_sizes; (void)n_in; (void)out_size; (void)ws_size;
  const int*   contexts  = (const int*)d_in[0];
  const int*   positions = (const int*)d_in[1];
  const float* emb   = (const float*)d_in[2];
  const float* wih0  = (const float*)d_in[3];
  const float* whh0  = (const float*)d_in[4];
  const float* bih0  = (const float*)d_in[5];
  const float* bhh0  = (const float*)d_in[6];
  const float* wih1  = (const float*)d_in[7];
  const float* whh1  = (const float*)d_in[8];
  const float* bih1  = (const float*)d_in[9];
  const float* bhh1  = (const float*)d_in[10];
  const float* wcls  = (const float*)d_in[11];
  const float* bcls  = (const float*)d_in[12];
  float* out = (float*)d_out;
  unsigned char* ws = (unsigned char*)d_ws;

  void* args[] = { &contexts, &positions, &emb,
                   &wih0, &whh0, &bih0, &bhh0,
                   &wih1, &whh1, &bih1, &bhh1,
                   &wcls, &bcls, &out, &ws };
  hipLaunchCooperativeKernel((const void*)ContextAwareModel_9655086481739_kernel,
                             dim3(256), dim3(128), args, 0, stream);
}

// Round 2
// 12477.533 us; speedup vs baseline: 1.2981x; 1.2981x over previous
//
#include <hip/hip_runtime.h>
#include <hip/hip_cooperative_groups.h>

// Persistent cooperative LSTM kernel.
// Grid = 256 WGs x 128 threads (2 waves). WG id decode:
//   layer = wg>>7, dir = (wg>>6)&1, colblk = (wg>>1)&31 (8 h-cols), mhalf = wg&1 (32 batch rows)
// Superstep k: layer0 computes t=k, layer1 computes t=k-1  -> ONE grid barrier per superstep.
// R1: replaced cg grid.sync() (~32 us each!) with hand-rolled sense-reversing
//     barrier + __threadfence for cross-XCD h-state visibility.

typedef short v8s __attribute__((ext_vector_type(8)));
typedef float v4f __attribute__((ext_vector_type(4)));

#define S_LEN 512
#define BATCH 64
#define EMBD  300
#define XPAD  320
#define ROWP0 584   // 320 (x, padded) + 256 (h) + 8 pad  -> bank stride 4 mod 32 (2-way, free)
#define ROWP1 776   // 512 (x1) + 256 (h) + 8 pad
#define NWG   256

__device__ inline unsigned short f2bf(float x) {
  union { float f; unsigned u; } v; v.f = x;
  unsigned r = v.u + 0x7FFF + ((v.u >> 16) & 1);   // RNE
  return (unsigned short)(r >> 16);
}
__device__ inline float sigm(float x) { return 1.f / (1.f + __expf(-x)); }
__device__ inline float tanhf_(float x) {
  float e = __expf(-2.f * fabsf(x));
  float r = (1.f - e) / (1.f + e);
  return x >= 0.f ? r : -r;
}

// Sense-reversing grid barrier. bar[0]/bar[64]: ping-pong arrival counters
// (256B apart), bar[32]: generation word. All agent-scope.
__device__ inline void grid_bar(unsigned* bar, unsigned& phase) {
  __syncthreads();                       // drains vmcnt for ALL waves of this WG
  if (threadIdx.x == 0) {
    __threadfence();                     // release: wbL2 -> h-state visible to other XCDs
    unsigned g = phase;
    unsigned* cnt = bar + ((g & 1) << 6);
    unsigned* gen = bar + 32;
    unsigned old = __hip_atomic_fetch_add(cnt, 1u, __ATOMIC_RELAXED, __HIP_MEMORY_SCOPE_AGENT);
    if (old == NWG - 1u) {
      __hip_atomic_store(cnt, 0u, __ATOMIC_RELAXED, __HIP_MEMORY_SCOPE_AGENT);
      __hip_atomic_store(gen, g + 1u, __ATOMIC_RELEASE, __HIP_MEMORY_SCOPE_AGENT);
    } else {
      while (__hip_atomic_load(gen, __ATOMIC_ACQUIRE, __HIP_MEMORY_SCOPE_AGENT) <= g) {
        __builtin_amdgcn_s_sleep(2);
      }
    }
    phase = g + 1u;
    __threadfence();                     // acquire: inv L1/L2 -> whole WG sees fresh h-state
  }
  __syncthreads();
}

// One step's dual-tile GEMM: acc0 = [i|f] tile, acc1 = [g|o] tile.
// All A fragments issued up-front (global, L2/LLC-hot) to hide latency; B from LDS.
template<int NK1, int NK2, int P2OFF>
__device__ inline void step_mm(const unsigned short* __restrict__ aP1,
                               const unsigned short* __restrict__ aP2,
                               const unsigned short* lds_t0,
                               const unsigned short* lds_t1,
                               v4f& acc0, v4f& acc1) {
  v8s a[NK1 + NK2];
#pragma unroll
  for (int i = 0; i < NK1; ++i) a[i] = *(const v8s*)(aP1 + i * 32);
#pragma unroll
  for (int i = 0; i < NK2; ++i) a[NK1 + i] = *(const v8s*)(aP2 + i * 32);
#pragma unroll
  for (int i = 0; i < NK1; ++i) {
    v8s b0 = *(const v8s*)(lds_t0 + i * 32);
    v8s b1 = *(const v8s*)(lds_t1 + i * 32);
    acc0 = __builtin_amdgcn_mfma_f32_16x16x32_bf16(a[i], b0, acc0, 0, 0, 0);
    acc1 = __builtin_amdgcn_mfma_f32_16x16x32_bf16(a[i], b1, acc1, 0, 0, 0);
  }
#pragma unroll
  for (int i = 0; i < NK2; ++i) {
    v8s b0 = *(const v8s*)(lds_t0 + P2OFF + i * 32);
    v8s b1 = *(const v8s*)(lds_t1 + P2OFF + i * 32);
    acc0 = __builtin_amdgcn_mfma_f32_16x16x32_bf16(a[NK1 + i], b0, acc0, 0, 0, 0);
    acc1 = __builtin_amdgcn_mfma_f32_16x16x32_bf16(a[NK1 + i], b1, acc1, 0, 0, 0);
  }
}

__global__ void __launch_bounds__(128, 1)
ContextAwareModel_9655086481739_kernel(
    const int* __restrict__ contexts, const int* __restrict__ positions,
    const float* __restrict__ emb,
    const float* __restrict__ wih0, const float* __restrict__ whh0,
    const float* __restrict__ bih0, const float* __restrict__ bhh0,
    const float* __restrict__ wih1, const float* __restrict__ whh1,
    const float* __restrict__ bih1, const float* __restrict__ bhh1,
    const float* __restrict__ wcls, const float* __restrict__ bcls,
    float* __restrict__ out, unsigned char* __restrict__ ws)
{
  __shared__ unsigned short smem[32 * ROWP1];   // 49,664 B

  const int wg   = blockIdx.x;
  const int tid  = threadIdx.x;
  const int layer  = wg >> 7;
  const int d      = (wg >> 6) & 1;
  const int colblk = (wg >> 1) & 31;
  const int mhalf  = wg & 1;
  const int wv   = tid >> 6;
  const int lane = tid & 63;
  const int quad = lane >> 4;
  const int lc   = lane & 15;
  const int hc0  = colblk * 8;
  const int hc   = hc0 + (lc & 7);
  const int m0   = mhalf * 32 + wv * 16;
  const int r_base = m0 + quad * 4;

  // workspace layout (bytes): Xbuf[512][64][320] bf16 | h0[2][64][512] bf16 |
  //                           h1[2][2][64][256] bf16 | tgt[64][512] f32 | barrier
  unsigned short* Xbuf  = (unsigned short*)ws;
  unsigned short* h0buf = (unsigned short*)(ws + 20971520u);
  unsigned short* h1buf = (unsigned short*)(ws + 20971520u + 131072u);
  float*          tgt   = (float*)(ws + 20971520u + 262144u);
  unsigned*       bar   = (unsigned*)(ws + 20971520u + 262144u + 131072u);

  const int ROWP = layer ? ROWP1 : ROWP0;

  // ---------------- stage 0 ----------------
  { // zero h-state (both parities, both layers; contiguous 131072 ushorts)
    for (int i = wg * 128 + tid; i < 131072; i += 256 * 128) h0buf[i] = 0;
    if (wg == 0 && tid < 128) bar[tid] = 0;      // barrier state (ws is poisoned!)
  }
  { // embedding gather -> bf16, padded to 320
    int gw2 = wg * 2 + wv;                     // 0..511 waves
    for (int rl = 0; rl < 64; ++rl) {
      int rr = gw2 * 64 + rl;                  // rr = t*64 + b
      int t = rr >> 6, b = rr & 63;
      int tok = contexts[b * S_LEN + t];
      const float* erow = emb + (long)tok * EMBD;
#pragma unroll
      for (int i = 0; i < 5; ++i) {
        int kk = i * 64 + lane;
        float v = (kk < EMBD) ? erow[kk] : 0.f;
        if (kk < XPAD) Xbuf[rr * XPAD + kk] = f2bf(v);
      }
    }
  }
  { // weights -> LDS (bf16). Row lr: tile T=lr>>4, col c=lr&15, gate = T*2+(c>>3)
    const float* wih = layer ? wih1 : wih0;
    const float* whh = layer ? whh1 : whh0;
    const int KI  = layer ? 512 : 300;
    const int KIp = layer ? 512 : 320;
    const int KT  = layer ? 768 : 576;
    int lr = tid >> 2, sub = tid & 3;
    int c = lr & 15, T = lr >> 4;
    int gate = T * 2 + (c >> 3);
    int j = gate * 256 + hc0 + (c & 7);
    const float* wri = wih + (long)(d * 1024 + j) * KI;
    const float* wrh = whh + (long)(d * 1024 + j) * 256;
    for (int kk = sub; kk < ROWP; kk += 4) {
      float v = 0.f;
      if (kk < KI) v = wri[kk];
      else if (kk >= KIp && kk < KT) v = wrh[kk - KIp];
      smem[lr * ROWP + kk] = f2bf(v);
    }
  }
  float bias0, bias1;
  {
    const float* bi = layer ? bih1 : bih0;
    const float* bh = layer ? bhh1 : bhh0;
    int j0 = ((lc >> 3) & 1) * 256 + hc;        // gate i/f
    int j1 = (2 + ((lc >> 3) & 1)) * 256 + hc;  // gate g/o
    bias0 = bi[d * 1024 + j0] + bh[d * 1024 + j0];
    bias1 = bi[d * 1024 + j1] + bh[d * 1024 + j1];
  }
  int pos[4];
#pragma unroll
  for (int j = 0; j < 4; ++j) pos[j] = positions[r_base + j];

  float cst[4] = {0.f, 0.f, 0.f, 0.f};

  const unsigned short* lds_t0 = smem + lc * ROWP + quad * 8;
  const unsigned short* lds_t1 = smem + (16 + lc) * ROWP + quad * 8;

  // one known-correct cooperative sync to publish zeroed barrier state + Xbuf
  cooperative_groups::grid_group gg = cooperative_groups::this_grid();
  __syncthreads();
  gg.sync();

  unsigned phase = 0;

  // ---------------- supersteps ----------------
  for (int k = 0; k <= S_LEN; ++k) {
    bool active = layer ? (k >= 1) : (k < S_LEN);
    if (active) {
      int t = layer ? (k - 1) : k;
      v4f acc0 = {bias0, bias0, bias0, bias0};
      v4f acc1 = {bias1, bias1, bias1, bias1};
      if (layer == 0) {
        // reads X_t and h0_{t-1} (parity (k-1)&1), writes h0_t (parity k&1)
        const unsigned short* aP1 = Xbuf + (t * BATCH + m0 + lc) * XPAD + quad * 8;
        const unsigned short* aP2 = h0buf + ((k + 1) & 1) * 32768 + (m0 + lc) * 512 + d * 256 + quad * 8;
        step_mm<10, 8, 320>(aP1, aP2, lds_t0, lds_t1, acc0, acc1);
      } else {
        // reads h0_t (parity t&1, written last superstep) and h1_{t-1}, writes h1_t
        const unsigned short* aP1 = h0buf + (t & 1) * 32768 + (m0 + lc) * 512 + quad * 8;
        const unsigned short* aP2 = h1buf + ((t + 1) & 1) * 32768 + d * 16384 + (m0 + lc) * 256 + quad * 8;
        step_mm<16, 8, 512>(aP1, aP2, lds_t0, lds_t1, acc0, acc1);
      }
      bool hi = (lc & 8) != 0;
#pragma unroll
      for (int j = 0; j < 4; ++j) {
        float a0 = acc0[j], a1 = acc1[j];
        float o0 = __shfl_xor(a0, 8);
        float o1 = __shfl_xor(a1, 8);
        float iv = hi ? o0 : a0;
        float fv = hi ? a0 : o0;
        float gv = hi ? o1 : a1;
        float ov = hi ? a1 : o1;
        float ii = sigm(iv), ff = sigm(fv), ggt = tanhf_(gv), oo = sigm(ov);
        float cn = ff * cst[j] + ii * ggt;
        cst[j] = cn;
        float hv = oo * tanhf_(cn);
        if (lc < 8) {   // lanes lc>=8 are duplicates after the shuffle
          unsigned short hb = f2bf(hv);
          int r = r_base + j;
          if (layer == 0) {
            h0buf[(k & 1) * 32768 + r * 512 + d * 256 + hc] = hb;
          } else {
            h1buf[(t & 1) * 32768 + d * 16384 + r * 256 + hc] = hb;
            if (pos[j] == t) tgt[r * 512 + d * 256 + hc] = hv;
          }
        }
      }
    }
    grid_bar(bar, phase);
  }

  // ---------------- epilogue ----------------
  {
    for (int i = wg * 128 + tid; i < BATCH * 512; i += 256 * 128) out[256 + i] = tgt[i];
    int gw = wg * 2 + wv;
    if (gw < 128) {                 // one wave per (b, class)
      int b = gw >> 1, cl = gw & 1;
      float s = 0.f;
#pragma unroll
      for (int i = 0; i < 8; ++i) {
        int j = i * 64 + lane;
        s += tgt[b * 512 + j] * wcls[cl * 512 + j];
      }
      s += __shfl_xor(s, 32); s += __shfl_xor(s, 16); s += __shfl_xor(s, 8);
      s += __shfl_xor(s, 4);  s += __shfl_xor(s, 2);  s += __shfl_xor(s, 1);
      if (lane == 0) {
        float L = s + bcls[cl];
        out[b * 2 + cl] = L;             // logits
        out[128 + b * 2 + cl] = sigm(L); // probs
      }
    }
  }
}

extern "C" void kernel_launch(void* const* d_in, const int* in_sizes, int n_in,
                              void* d_out, int out_size, void* d_ws, size_t ws_size,
                              hipStream_t stream) {
  (void)in_sizes; (void)n_in; (void)out_size; (void)ws_size;
  const int*   contexts  = (const int*)d_in[0];
  const int*   positions = (const int*)d_in[1];
  const float* emb   = (const float*)d_in[2];
  const float* wih0  = (const float*)d_in[3];
  const float* whh0  = (const float*)d_in[4];
  const float* bih0  = (const float*)d_in[5];
  const float* bhh0  = (const float*)d_in[6];
  const float* wih1  = (const float*)d_in[7];
  const float* whh1  = (const float*)d_in[8];
  const float* bih1  = (const float*)d_in[9];
  const float* bhh1  = (const float*)d_in[10];
  const float* wcls  = (const float*)d_in[11];
  const float* bcls  = (const float*)d_in[12];
  float* out = (float*)d_out;
  unsigned char* ws = (unsigned char*)d_ws;

  void* args[] = { &contexts, &positions, &emb,
                   &wih0, &whh0, &bih0, &bhh0,
                   &wih1, &whh1, &bih1, &bhh1,
                   &wcls, &bcls, &out, &ws };
  hipLaunchCooperativeKernel((const void*)ContextAwareModel_9655086481739_kernel,
                             dim3(256), dim3(128), args, 0, stream);
}

// Round 3
// 3900.293 us; speedup vs baseline: 4.1528x; 3.1991x over previous
//
#include <hip/hip_runtime.h>
#include <hip/hip_cooperative_groups.h>

// Persistent cooperative LSTM kernel.
// Grid = 256 WGs x 128 threads (2 waves). WG id decode:
//   layer = wg>>7, dir = (wg>>6)&1, colblk = (wg>>1)&31 (8 h-cols), mhalf = wg&1 (32 batch rows)
// Superstep k: layer0 computes t=k, layer1 computes t=k-1  -> ONE grid barrier per superstep.
// R1: replaced cg grid.sync() (~32us) with hand-rolled barrier + threadfence  -> 24us/step.
// R2: threadfence (buffer_wbl2/buffer_inv L2 walks) was the real cost. Removed ALL cache
//     maintenance: h-state/tgt moved to system-scope relaxed atomics (sc0 sc1 -> coherent
//     at IC, bypass L1/L2); barrier uses relaxed atomics + vmcnt drain only.

typedef short v8s __attribute__((ext_vector_type(8)));
typedef float v4f __attribute__((ext_vector_type(4)));
typedef unsigned long long u64;

#define S_LEN 512
#define BATCH 64
#define EMBD  300
#define XPAD  320
#define ROWP0 584   // 320 (x, padded) + 256 (h) + 8 pad  -> bank stride 4 mod 32 (2-way, free)
#define ROWP1 776   // 512 (x1) + 256 (h) + 8 pad
#define NWG   256

__device__ inline unsigned short f2bf(float x) {
  union { float f; unsigned u; } v; v.f = x;
  unsigned r = v.u + 0x7FFF + ((v.u >> 16) & 1);   // RNE
  return (unsigned short)(r >> 16);
}
__device__ inline float sigm(float x) { return 1.f / (1.f + __expf(-x)); }
__device__ inline float tanhf_(float x) {
  float e = __expf(-2.f * fabsf(x));
  float r = (1.f - e) / (1.f + e);
  return x >= 0.f ? r : -r;
}

// Coherent (sc0 sc1, IC-served) accessors — no cache maintenance needed anywhere.
__device__ inline v8s ld_sys16(const unsigned short* p) {
  union { u64 q[2]; v8s s; } u;
  u.q[0] = __hip_atomic_load((const u64*)p,     __ATOMIC_RELAXED, __HIP_MEMORY_SCOPE_SYSTEM);
  u.q[1] = __hip_atomic_load((const u64*)p + 1, __ATOMIC_RELAXED, __HIP_MEMORY_SCOPE_SYSTEM);
  return u.s;
}
__device__ inline float ldf_sys(const float* p) {
  return __hip_atomic_load(p, __ATOMIC_RELAXED, __HIP_MEMORY_SCOPE_SYSTEM);
}
__device__ inline void st4_sys(unsigned* p, unsigned v) {
  __hip_atomic_store(p, v, __ATOMIC_RELAXED, __HIP_MEMORY_SCOPE_SYSTEM);
}
__device__ inline void stf_sys(float* p, float v) {
  __hip_atomic_store(p, v, __ATOMIC_RELAXED, __HIP_MEMORY_SCOPE_SYSTEM);
}

// Sense-reversing grid barrier, NO fences. Prior h-stores are write-through (sc0 sc1),
// drained by the explicit vmcnt wait below, so relaxed atomics suffice.
__device__ inline void grid_bar(unsigned* bar, unsigned& phase) {
  asm volatile("s_waitcnt vmcnt(0)" ::: "memory");  // every wave drains its own stores
  __syncthreads();
  if (threadIdx.x == 0) {
    unsigned g = phase;
    unsigned* cnt = bar + ((g & 1) << 6);
    unsigned* gen = bar + 32;
    unsigned old = __hip_atomic_fetch_add(cnt, 1u, __ATOMIC_RELAXED, __HIP_MEMORY_SCOPE_AGENT);
    if (old == NWG - 1u) {
      __hip_atomic_store(cnt, 0u, __ATOMIC_RELAXED, __HIP_MEMORY_SCOPE_AGENT);
      __hip_atomic_store(gen, g + 1u, __ATOMIC_RELAXED, __HIP_MEMORY_SCOPE_AGENT);
    } else {
      while (__hip_atomic_load(gen, __ATOMIC_RELAXED, __HIP_MEMORY_SCOPE_AGENT) <= g) {
        __builtin_amdgcn_s_sleep(1);
      }
    }
    phase = g + 1u;
  }
  __syncthreads();
}

// One step's dual-tile GEMM: acc0 = [i|f] tile, acc1 = [g|o] tile.
// A-part1 (C1) / A-part2 (C2) optionally coherent; B from LDS.
template<int NK1, int NK2, int P2OFF, bool C1, bool C2>
__device__ inline void step_mm(const unsigned short* __restrict__ aP1,
                               const unsigned short* __restrict__ aP2,
                               const unsigned short* lds_t0,
                               const unsigned short* lds_t1,
                               v4f& acc0, v4f& acc1) {
  v8s a[NK1 + NK2];
#pragma unroll
  for (int i = 0; i < NK1; ++i)
    a[i] = C1 ? ld_sys16(aP1 + i * 32) : *(const v8s*)(aP1 + i * 32);
#pragma unroll
  for (int i = 0; i < NK2; ++i)
    a[NK1 + i] = C2 ? ld_sys16(aP2 + i * 32) : *(const v8s*)(aP2 + i * 32);
#pragma unroll
  for (int i = 0; i < NK1; ++i) {
    v8s b0 = *(const v8s*)(lds_t0 + i * 32);
    v8s b1 = *(const v8s*)(lds_t1 + i * 32);
    acc0 = __builtin_amdgcn_mfma_f32_16x16x32_bf16(a[i], b0, acc0, 0, 0, 0);
    acc1 = __builtin_amdgcn_mfma_f32_16x16x32_bf16(a[i], b1, acc1, 0, 0, 0);
  }
#pragma unroll
  for (int i = 0; i < NK2; ++i) {
    v8s b0 = *(const v8s*)(lds_t0 + P2OFF + i * 32);
    v8s b1 = *(const v8s*)(lds_t1 + P2OFF + i * 32);
    acc0 = __builtin_amdgcn_mfma_f32_16x16x32_bf16(a[NK1 + i], b0, acc0, 0, 0, 0);
    acc1 = __builtin_amdgcn_mfma_f32_16x16x32_bf16(a[NK1 + i], b1, acc1, 0, 0, 0);
  }
}

__global__ void __launch_bounds__(128, 1)
ContextAwareModel_9655086481739_kernel(
    const int* __restrict__ contexts, const int* __restrict__ positions,
    const float* __restrict__ emb,
    const float* __restrict__ wih0, const float* __restrict__ whh0,
    const float* __restrict__ bih0, const float* __restrict__ bhh0,
    const float* __restrict__ wih1, const float* __restrict__ whh1,
    const float* __restrict__ bih1, const float* __restrict__ bhh1,
    const float* __restrict__ wcls, const float* __restrict__ bcls,
    float* __restrict__ out, unsigned char* __restrict__ ws)
{
  __shared__ unsigned short smem[32 * ROWP1];   // 49,664 B

  const int wg   = blockIdx.x;
  const int tid  = threadIdx.x;
  const int layer  = wg >> 7;
  const int d      = (wg >> 6) & 1;
  const int colblk = (wg >> 1) & 31;
  const int mhalf  = wg & 1;
  const int wv   = tid >> 6;
  const int lane = tid & 63;
  const int quad = lane >> 4;
  const int lc   = lane & 15;
  const int hc0  = colblk * 8;
  const int hc   = hc0 + (lc & 7);
  const int m0   = mhalf * 32 + wv * 16;
  const int r_base = m0 + quad * 4;

  // workspace layout (bytes): Xbuf[512][64][320] bf16 | h0[2][64][512] bf16 |
  //                           h1[2][2][64][256] bf16 | tgt[64][512] f32 | barrier
  unsigned short* Xbuf  = (unsigned short*)ws;
  unsigned short* h0buf = (unsigned short*)(ws + 20971520u);
  unsigned short* h1buf = (unsigned short*)(ws + 20971520u + 131072u);
  float*          tgt   = (float*)(ws + 20971520u + 262144u);
  unsigned*       bar   = (unsigned*)(ws + 20971520u + 262144u + 131072u);

  const int ROWP = layer ? ROWP1 : ROWP0;

  // ---------------- stage 0 ----------------
  { // zero h-state (both parities, both layers; contiguous 131072 ushorts)
    for (int i = wg * 128 + tid; i < 131072; i += 256 * 128) h0buf[i] = 0;
    if (wg == 0 && tid < 128) bar[tid] = 0;      // barrier state (ws is poisoned!)
  }
  { // embedding gather -> bf16, padded to 320
    int gw2 = wg * 2 + wv;                     // 0..511 waves
    for (int rl = 0; rl < 64; ++rl) {
      int rr = gw2 * 64 + rl;                  // rr = t*64 + b
      int t = rr >> 6, b = rr & 63;
      int tok = contexts[b * S_LEN + t];
      const float* erow = emb + (long)tok * EMBD;
#pragma unroll
      for (int i = 0; i < 5; ++i) {
        int kk = i * 64 + lane;
        float v = (kk < EMBD) ? erow[kk] : 0.f;
        if (kk < XPAD) Xbuf[rr * XPAD + kk] = f2bf(v);
      }
    }
  }
  { // weights -> LDS (bf16). Row lr: tile T=lr>>4, col c=lr&15, gate = T*2+(c>>3)
    const float* wih = layer ? wih1 : wih0;
    const float* whh = layer ? whh1 : whh0;
    const int KI  = layer ? 512 : 300;
    const int KIp = layer ? 512 : 320;
    const int KT  = layer ? 768 : 576;
    int lr = tid >> 2, sub = tid & 3;
    int c = lr & 15, T = lr >> 4;
    int gate = T * 2 + (c >> 3);
    int j = gate * 256 + hc0 + (c & 7);
    const float* wri = wih + (long)(d * 1024 + j) * KI;
    const float* wrh = whh + (long)(d * 1024 + j) * 256;
    for (int kk = sub; kk < ROWP; kk += 4) {
      float v = 0.f;
      if (kk < KI) v = wri[kk];
      else if (kk >= KIp && kk < KT) v = wrh[kk - KIp];
      smem[lr * ROWP + kk] = f2bf(v);
    }
  }
  float bias0, bias1;
  {
    const float* bi = layer ? bih1 : bih0;
    const float* bh = layer ? bhh1 : bhh0;
    int j0 = ((lc >> 3) & 1) * 256 + hc;        // gate i/f
    int j1 = (2 + ((lc >> 3) & 1)) * 256 + hc;  // gate g/o
    bias0 = bi[d * 1024 + j0] + bh[d * 1024 + j0];
    bias1 = bi[d * 1024 + j1] + bh[d * 1024 + j1];
  }
  int pos[4];
#pragma unroll
  for (int j = 0; j < 4; ++j) pos[j] = positions[r_base + j];

  float cst[4] = {0.f, 0.f, 0.f, 0.f};

  const unsigned short* lds_t0 = smem + lc * ROWP + quad * 8;
  const unsigned short* lds_t1 = smem + (16 + lc) * ROWP + quad * 8;

  // one known-correct cooperative sync to publish zeroed h/barrier state + Xbuf
  cooperative_groups::grid_group gg = cooperative_groups::this_grid();
  __syncthreads();
  gg.sync();

  unsigned phase = 0;

  // ---------------- supersteps ----------------
  for (int k = 0; k <= S_LEN; ++k) {
    bool active = layer ? (k >= 1) : (k < S_LEN);
    if (active) {
      int t = layer ? (k - 1) : k;
      v4f acc0 = {bias0, bias0, bias0, bias0};
      v4f acc1 = {bias1, bias1, bias1, bias1};
      if (layer == 0) {
        // reads X_t (cached) and h0_{t-1} (coherent), writes h0_t (parity k&1)
        const unsigned short* aP1 = Xbuf + (t * BATCH + m0 + lc) * XPAD + quad * 8;
        const unsigned short* aP2 = h0buf + ((k + 1) & 1) * 32768 + (m0 + lc) * 512 + d * 256 + quad * 8;
        step_mm<10, 8, 320, false, true>(aP1, aP2, lds_t0, lds_t1, acc0, acc1);
      } else {
        // reads h0_t (coherent) and h1_{t-1} (coherent), writes h1_t
        const unsigned short* aP1 = h0buf + (t & 1) * 32768 + (m0 + lc) * 512 + quad * 8;
        const unsigned short* aP2 = h1buf + ((t + 1) & 1) * 32768 + d * 16384 + (m0 + lc) * 256 + quad * 8;
        step_mm<16, 8, 512, true, true>(aP1, aP2, lds_t0, lds_t1, acc0, acc1);
      }
      bool hi = (lc & 8) != 0;
#pragma unroll
      for (int j = 0; j < 4; ++j) {
        float a0 = acc0[j], a1 = acc1[j];
        float o0 = __shfl_xor(a0, 8);
        float o1 = __shfl_xor(a1, 8);
        float iv = hi ? o0 : a0;
        float fv = hi ? a0 : o0;
        float gv = hi ? o1 : a1;
        float ov = hi ? a1 : o1;
        float ii = sigm(iv), ff = sigm(fv), ggt = tanhf_(gv), oo = sigm(ov);
        float cn = ff * cst[j] + ii * ggt;
        cst[j] = cn;
        float hv = oo * tanhf_(cn);
        int r = r_base + j;
        // pair lanes (lc even|odd) into one 4B coherent store
        unsigned hb = f2bf(hv);
        unsigned ob = ((unsigned)__shfl_xor((int)hb, 1)) & 0xFFFFu;
        if (lc < 8 && !(lc & 1)) {
          unsigned word = hb | (ob << 16);     // low short = even hc (little-endian)
          if (layer == 0) {
            st4_sys((unsigned*)&h0buf[(k & 1) * 32768 + r * 512 + d * 256 + hc], word);
          } else {
            st4_sys((unsigned*)&h1buf[(t & 1) * 32768 + d * 16384 + r * 256 + hc], word);
          }
        }
        if (layer == 1 && lc < 8 && pos[j] == t) stf_sys(&tgt[r * 512 + d * 256 + hc], hv);
      }
    }
    grid_bar(bar, phase);
  }

  // ---------------- epilogue ----------------
  {
    for (int i = wg * 128 + tid; i < BATCH * 512; i += 256 * 128) out[256 + i] = ldf_sys(&tgt[i]);
    int gw = wg * 2 + wv;
    if (gw < 128) {                 // one wave per (b, class)
      int b = gw >> 1, cl = gw & 1;
      float s = 0.f;
#pragma unroll
      for (int i = 0; i < 8; ++i) {
        int j = i * 64 + lane;
        s += ldf_sys(&tgt[b * 512 + j]) * wcls[cl * 512 + j];
      }
      s += __shfl_xor(s, 32); s += __shfl_xor(s, 16); s += __shfl_xor(s, 8);
      s += __shfl_xor(s, 4);  s += __shfl_xor(s, 2);  s += __shfl_xor(s, 1);
      if (lane == 0) {
        float L = s + bcls[cl];
        out[b * 2 + cl] = L;             // logits
        out[128 + b * 2 + cl] = sigm(L); // probs
      }
    }
  }
}

extern "C" void kernel_launch(void* const* d_in, const int* in_sizes, int n_in,
                              void* d_out, int out_size, void* d_ws, size_t ws_size,
                              hipStream_t stream) {
  (void)in_sizes; (void)n_in; (void)out_size; (void)ws_size;
  const int*   contexts  = (const int*)d_in[0];
  const int*   positions = (const int*)d_in[1];
  const float* emb   = (const float*)d_in[2];
  const float* wih0  = (const float*)d_in[3];
  const float* whh0  = (const float*)d_in[4];
  const float* bih0  = (const float*)d_in[5];
  const float* bhh0  = (const float*)d_in[6];
  const float* wih1  = (const float*)d_in[7];
  const float* whh1  = (const float*)d_in[8];
  const float* bih1  = (const float*)d_in[9];
  const float* bhh1  = (const float*)d_in[10];
  const float* wcls  = (const float*)d_in[11];
  const float* bcls  = (const float*)d_in[12];
  float* out = (float*)d_out;
  unsigned char* ws = (unsigned char*)d_ws;

  void* args[] = { &contexts, &positions, &emb,
                   &wih0, &whh0, &bih0, &bhh0,
                   &wih1, &whh1, &bih1, &bhh1,
                   &wcls, &bcls, &out, &ws };
  hipLaunchCooperativeKernel((const void*)ContextAwareModel_9655086481739_kernel,
                             dim3(256), dim3(128), args, 0, stream);
}

// Round 4
// 3627.188 us; speedup vs baseline: 4.4655x; 1.0753x over previous
//
#include <hip/hip_runtime.h>
#include <hip/hip_cooperative_groups.h>

// Persistent cooperative LSTM kernel.
// Grid = 256 WGs x 128 threads (2 waves). WG id decode:
//   layer = wg>>7, dir = (wg>>6)&1, colblk = (wg>>1)&31 (8 h-cols), mhalf = wg&1 (32 batch rows)
// R1: cg grid.sync (~32us/step) -> hand barrier+fences: 24us/step.
// R2: removed cache maintenance; coherent sc0sc1 data path + relaxed barrier: 7.3us/step.
// R3: global 256-WG barrier -> 8 independent 32-WG group pipelines with monotonic
//     aggregate counters (producer/consumer flags). h0 ring deepened to 4 parities so
//     layer0 only needs layer1 >= t-3 (off critical path). Four decoupled chains.

typedef short v8s __attribute__((ext_vector_type(8)));
typedef float v4f __attribute__((ext_vector_type(4)));
typedef unsigned long long u64;

#define S_LEN 512
#define BATCH 64
#define EMBD  300
#define XPAD  320
#define ROWP0 584   // 320 (x, padded) + 256 (h) + 8 pad
#define ROWP1 776   // 512 (x1) + 256 (h) + 8 pad

__device__ inline unsigned short f2bf(float x) {
  union { float f; unsigned u; } v; v.f = x;
  unsigned r = v.u + 0x7FFF + ((v.u >> 16) & 1);   // RNE
  return (unsigned short)(r >> 16);
}
__device__ inline float sigm(float x) { return 1.f / (1.f + __expf(-x)); }
__device__ inline float tanhf_(float x) {
  float e = __expf(-2.f * fabsf(x));
  float r = (1.f - e) / (1.f + e);
  return x >= 0.f ? r : -r;
}

// Coherent (sc0 sc1, IC-served) accessors — no cache maintenance anywhere.
__device__ inline v8s ld_sys16(const unsigned short* p) {
  union { u64 q[2]; v8s s; } u;
  u.q[0] = __hip_atomic_load((const u64*)p,     __ATOMIC_RELAXED, __HIP_MEMORY_SCOPE_SYSTEM);
  u.q[1] = __hip_atomic_load((const u64*)p + 1, __ATOMIC_RELAXED, __HIP_MEMORY_SCOPE_SYSTEM);
  return u.s;
}
__device__ inline float ldf_sys(const float* p) {
  return __hip_atomic_load(p, __ATOMIC_RELAXED, __HIP_MEMORY_SCOPE_SYSTEM);
}
__device__ inline void st4_sys(unsigned* p, unsigned v) {
  __hip_atomic_store(p, v, __ATOMIC_RELAXED, __HIP_MEMORY_SCOPE_SYSTEM);
}
__device__ inline void stf_sys(float* p, float v) {
  __hip_atomic_store(p, v, __ATOMIC_RELAXED, __HIP_MEMORY_SCOPE_SYSTEM);
}

__device__ inline void wait_ge(unsigned* c, unsigned thr) {
  while (__hip_atomic_load(c, __ATOMIC_RELAXED, __HIP_MEMORY_SCOPE_AGENT) < thr)
    __builtin_amdgcn_s_sleep(1);
}
__device__ inline void arrive(unsigned* c) {
  __hip_atomic_fetch_add(c, 1u, __ATOMIC_RELAXED, __HIP_MEMORY_SCOPE_AGENT);
}

// One step's dual-tile GEMM: acc0 = [i|f] tile, acc1 = [g|o] tile.
template<int NK1, int NK2, int P2OFF, bool C1, bool C2>
__device__ inline void step_mm(const unsigned short* __restrict__ aP1,
                               const unsigned short* __restrict__ aP2,
                               const unsigned short* lds_t0,
                               const unsigned short* lds_t1,
                               v4f& acc0, v4f& acc1) {
  v8s a[NK1 + NK2];
#pragma unroll
  for (int i = 0; i < NK1; ++i)
    a[i] = C1 ? ld_sys16(aP1 + i * 32) : *(const v8s*)(aP1 + i * 32);
#pragma unroll
  for (int i = 0; i < NK2; ++i)
    a[NK1 + i] = C2 ? ld_sys16(aP2 + i * 32) : *(const v8s*)(aP2 + i * 32);
#pragma unroll
  for (int i = 0; i < NK1; ++i) {
    v8s b0 = *(const v8s*)(lds_t0 + i * 32);
    v8s b1 = *(const v8s*)(lds_t1 + i * 32);
    acc0 = __builtin_amdgcn_mfma_f32_16x16x32_bf16(a[i], b0, acc0, 0, 0, 0);
    acc1 = __builtin_amdgcn_mfma_f32_16x16x32_bf16(a[i], b1, acc1, 0, 0, 0);
  }
#pragma unroll
  for (int i = 0; i < NK2; ++i) {
    v8s b0 = *(const v8s*)(lds_t0 + P2OFF + i * 32);
    v8s b1 = *(const v8s*)(lds_t1 + P2OFF + i * 32);
    acc0 = __builtin_amdgcn_mfma_f32_16x16x32_bf16(a[NK1 + i], b0, acc0, 0, 0, 0);
    acc1 = __builtin_amdgcn_mfma_f32_16x16x32_bf16(a[NK1 + i], b1, acc1, 0, 0, 0);
  }
}

__global__ void __launch_bounds__(128, 1)
ContextAwareModel_9655086481739_kernel(
    const int* __restrict__ contexts, const int* __restrict__ positions,
    const float* __restrict__ emb,
    const float* __restrict__ wih0, const float* __restrict__ whh0,
    const float* __restrict__ bih0, const float* __restrict__ bhh0,
    const float* __restrict__ wih1, const float* __restrict__ whh1,
    const float* __restrict__ bih1, const float* __restrict__ bhh1,
    const float* __restrict__ wcls, const float* __restrict__ bcls,
    float* __restrict__ out, unsigned char* __restrict__ ws)
{
  __shared__ unsigned short smem[32 * ROWP1];   // 49,664 B

  const int wg   = blockIdx.x;
  const int tid  = threadIdx.x;
  const int layer  = wg >> 7;
  const int d      = (wg >> 6) & 1;
  const int colblk = (wg >> 1) & 31;
  const int mhalf  = wg & 1;
  const int wv   = tid >> 6;
  const int lane = tid & 63;
  const int quad = lane >> 4;
  const int lc   = lane & 15;
  const int hc0  = colblk * 8;
  const int hc   = hc0 + (lc & 7);
  const int m0   = mhalf * 32 + wv * 16;
  const int r_base = m0 + quad * 4;

  // workspace layout (bytes):
  //   Xbuf[512][64][320] bf16                     @ 0         (20,971,520)
  //   h0  [4][64][512]  bf16  (4-deep ring)       @ 20971520  (262,144)
  //   h1  [2][2][64][256] bf16                    @ 21233664  (131,072)
  //   tgt [64][512] f32                           @ 21364736  (131,072)
  //   cnt [8] group counters, 256B stride         @ 21495808
  unsigned short* Xbuf  = (unsigned short*)ws;
  unsigned short* h0buf = (unsigned short*)(ws + 20971520u);
  unsigned short* h1buf = (unsigned short*)(ws + 20971520u + 262144u);
  float*          tgt   = (float*)(ws + 20971520u + 262144u + 131072u);
  unsigned*       cnt   = (unsigned*)(ws + 20971520u + 262144u + 131072u + 131072u);
  // counter index: (layer*4 + d*2 + mhalf) * 64

  const int ROWP = layer ? ROWP1 : ROWP0;

  // ---------------- stage 0 ----------------
  { // zero h-state (h0 4 parities + h1 2 parities, contiguous 196608 shorts)
    for (int i = wg * 128 + tid; i < 196608; i += 256 * 128) h0buf[i] = 0;
    if (wg == 0) { for (int i = tid; i < 512; i += 128) cnt[i] = 0; }
  }
  { // embedding gather -> bf16, padded to 320
    int gw2 = wg * 2 + wv;                     // 0..511 waves
    for (int rl = 0; rl < 64; ++rl) {
      int rr = gw2 * 64 + rl;                  // rr = t*64 + b
      int t = rr >> 6, b = rr & 63;
      int tok = contexts[b * S_LEN + t];
      const float* erow = emb + (long)tok * EMBD;
#pragma unroll
      for (int i = 0; i < 5; ++i) {
        int kk = i * 64 + lane;
        float v = (kk < EMBD) ? erow[kk] : 0.f;
        if (kk < XPAD) Xbuf[rr * XPAD + kk] = f2bf(v);
      }
    }
  }
  { // weights -> LDS (bf16). Row lr: tile T=lr>>4, col c=lr&15, gate = T*2+(c>>3)
    const float* wih = layer ? wih1 : wih0;
    const float* whh = layer ? whh1 : whh0;
    const int KI  = layer ? 512 : 300;
    const int KIp = layer ? 512 : 320;
    const int KT  = layer ? 768 : 576;
    int lr = tid >> 2, sub = tid & 3;
    int c = lr & 15, T = lr >> 4;
    int gate = T * 2 + (c >> 3);
    int j = gate * 256 + hc0 + (c & 7);
    const float* wri = wih + (long)(d * 1024 + j) * KI;
    const float* wrh = whh + (long)(d * 1024 + j) * 256;
    for (int kk = sub; kk < ROWP; kk += 4) {
      float v = 0.f;
      if (kk < KI) v = wri[kk];
      else if (kk >= KIp && kk < KT) v = wrh[kk - KIp];
      smem[lr * ROWP + kk] = f2bf(v);
    }
  }
  float bias0, bias1;
  {
    const float* bi = layer ? bih1 : bih0;
    const float* bh = layer ? bhh1 : bhh0;
    int j0 = ((lc >> 3) & 1) * 256 + hc;        // gate i/f
    int j1 = (2 + ((lc >> 3) & 1)) * 256 + hc;  // gate g/o
    bias0 = bi[d * 1024 + j0] + bh[d * 1024 + j0];
    bias1 = bi[d * 1024 + j1] + bh[d * 1024 + j1];
  }
  int pos[4];
#pragma unroll
  for (int j = 0; j < 4; ++j) pos[j] = positions[r_base + j];

  float cst[4] = {0.f, 0.f, 0.f, 0.f};

  const unsigned short* lds_t0 = smem + lc * ROWP + quad * 8;
  const unsigned short* lds_t1 = smem + (16 + lc) * ROWP + quad * 8;

  // one known-correct cooperative sync: publishes (via its wbL2) Xbuf, zeroed
  // h-state and zeroed counters to the coherent point for everyone.
  cooperative_groups::grid_group gg = cooperative_groups::this_grid();
  __syncthreads();
  gg.sync();

  const bool hi = (lc & 8) != 0;

  // ---------------- recurrence: four decoupled group chains ----------------
  if (layer == 0) {
    unsigned* c_own = cnt + (0 + d * 2 + mhalf) * 64;
    unsigned* c_l1a = cnt + (4 + 0 + mhalf) * 64;
    unsigned* c_l1b = cnt + (4 + 2 + mhalf) * 64;
    for (int t = 0; t < S_LEN; ++t) {
      if (tid == 0) {
        if (t) wait_ge(c_own, 32u * t);                 // own group finished t-1
        if (t >= 4) {                                   // h0 ring back-pressure
          unsigned thr = 32u * (t - 3);
          wait_ge(c_l1a, thr); wait_ge(c_l1b, thr);
        }
      }
      __syncthreads();
      v4f acc0 = {bias0, bias0, bias0, bias0};
      v4f acc1 = {bias1, bias1, bias1, bias1};
      const unsigned short* aP1 = Xbuf + (t * BATCH + m0 + lc) * XPAD + quad * 8;
      const unsigned short* aP2 = h0buf + ((t + 3) & 3) * 32768 + (m0 + lc) * 512 + d * 256 + quad * 8;
      step_mm<10, 8, 320, false, true>(aP1, aP2, lds_t0, lds_t1, acc0, acc1);
#pragma unroll
      for (int j = 0; j < 4; ++j) {
        float a0 = acc0[j], a1 = acc1[j];
        float o0 = __shfl_xor(a0, 8);
        float o1 = __shfl_xor(a1, 8);
        float iv = hi ? o0 : a0;
        float fv = hi ? a0 : o0;
        float gv = hi ? o1 : a1;
        float ov = hi ? a1 : o1;
        float ii = sigm(iv), ff = sigm(fv), ggt = tanhf_(gv), oo = sigm(ov);
        float cn = ff * cst[j] + ii * ggt;
        cst[j] = cn;
        float hv = oo * tanhf_(cn);
        unsigned hb = f2bf(hv);
        unsigned ob = ((unsigned)__shfl_xor((int)hb, 1)) & 0xFFFFu;
        if (lc < 8 && !(lc & 1)) {
          unsigned word = hb | (ob << 16);
          st4_sys((unsigned*)&h0buf[(t & 3) * 32768 + (r_base + j) * 512 + d * 256 + hc], word);
        }
      }
      asm volatile("s_waitcnt vmcnt(0)" ::: "memory");
      __syncthreads();
      if (tid == 0) arrive(c_own);
    }
  } else {
    unsigned* c_own = cnt + (4 + d * 2 + mhalf) * 64;
    unsigned* c_h0a = cnt + (0 + 0 + mhalf) * 64;
    unsigned* c_h0b = cnt + (0 + 2 + mhalf) * 64;
    for (int t = 0; t < S_LEN; ++t) {
      if (tid == 0) {
        unsigned thr = 32u * (t + 1);
        wait_ge(c_h0a, thr); wait_ge(c_h0b, thr);       // h0_t ready (both dirs)
        if (t) wait_ge(c_own, 32u * t);                 // own group finished t-1
      }
      __syncthreads();
      v4f acc0 = {bias0, bias0, bias0, bias0};
      v4f acc1 = {bias1, bias1, bias1, bias1};
      const unsigned short* aP1 = h0buf + (t & 3) * 32768 + (m0 + lc) * 512 + quad * 8;
      const unsigned short* aP2 = h1buf + ((t + 1) & 1) * 32768 + d * 16384 + (m0 + lc) * 256 + quad * 8;
      step_mm<16, 8, 512, true, true>(aP1, aP2, lds_t0, lds_t1, acc0, acc1);
#pragma unroll
      for (int j = 0; j < 4; ++j) {
        float a0 = acc0[j], a1 = acc1[j];
        float o0 = __shfl_xor(a0, 8);
        float o1 = __shfl_xor(a1, 8);
        float iv = hi ? o0 : a0;
        float fv = hi ? a0 : o0;
        float gv = hi ? o1 : a1;
        float ov = hi ? a1 : o1;
        float ii = sigm(iv), ff = sigm(fv), ggt = tanhf_(gv), oo = sigm(ov);
        float cn = ff * cst[j] + ii * ggt;
        cst[j] = cn;
        float hv = oo * tanhf_(cn);
        unsigned hb = f2bf(hv);
        unsigned ob = ((unsigned)__shfl_xor((int)hb, 1)) & 0xFFFFu;
        int r = r_base + j;
        if (lc < 8 && !(lc & 1)) {
          unsigned word = hb | (ob << 16);
          st4_sys((unsigned*)&h1buf[(t & 1) * 32768 + d * 16384 + r * 256 + hc], word);
        }
        if (lc < 8 && pos[j] == t) stf_sys(&tgt[r * 512 + d * 256 + hc], hv);
      }
      asm volatile("s_waitcnt vmcnt(0)" ::: "memory");
      __syncthreads();
      if (tid == 0) arrive(c_own);
    }
  }

  // final join: all layer-1 groups done -> tgt complete
  if (tid == 0) {
#pragma unroll
    for (int g = 4; g < 8; ++g) wait_ge(cnt + g * 64, 32u * S_LEN);
  }
  __syncthreads();

  // ---------------- epilogue ----------------
  {
    for (int i = wg * 128 + tid; i < BATCH * 512; i += 256 * 128) out[256 + i] = ldf_sys(&tgt[i]);
    int gw = wg * 2 + wv;
    if (gw < 128) {                 // one wave per (b, class)
      int b = gw >> 1, cl = gw & 1;
      float s = 0.f;
#pragma unroll
      for (int i = 0; i < 8; ++i) {
        int j = i * 64 + lane;
        s += ldf_sys(&tgt[b * 512 + j]) * wcls[cl * 512 + j];
      }
      s += __shfl_xor(s, 32); s += __shfl_xor(s, 16); s += __shfl_xor(s, 8);
      s += __shfl_xor(s, 4);  s += __shfl_xor(s, 2);  s += __shfl_xor(s, 1);
      if (lane == 0) {
        float L = s + bcls[cl];
        out[b * 2 + cl] = L;             // logits
        out[128 + b * 2 + cl] = sigm(L); // probs
      }
    }
  }
}

extern "C" void kernel_launch(void* const* d_in, const int* in_sizes, int n_in,
                              void* d_out, int out_size, void* d_ws, size_t ws_size,
                              hipStream_t stream) {
  (void)in_sizes; (void)n_in; (void)out_size; (void)ws_size;
  const int*   contexts  = (const int*)d_in[0];
  const int*   positions = (const int*)d_in[1];
  const float* emb   = (const float*)d_in[2];
  const float* wih0  = (const float*)d_in[3];
  const float* whh0  = (const float*)d_in[4];
  const float* bih0  = (const float*)d_in[5];
  const float* bhh0  = (const float*)d_in[6];
  const float* wih1  = (const float*)d_in[7];
  const float* whh1  = (const float*)d_in[8];
  const float* bih1  = (const float*)d_in[9];
  const float* bhh1  = (const float*)d_in[10];
  const float* wcls  = (const float*)d_in[11];
  const float* bcls  = (const float*)d_in[12];
  float* out = (float*)d_out;
  unsigned char* ws = (unsigned char*)d_ws;

  void* args[] = { &contexts, &positions, &emb,
                   &wih0, &whh0, &bih0, &bhh0,
                   &wih1, &whh1, &bih1, &bhh1,
                   &wcls, &bcls, &out, &ws };
  hipLaunchCooperativeKernel((const void*)ContextAwareModel_9655086481739_kernel,
                             dim3(256), dim3(128), args, 0, stream);
}

// Round 6
// 3068.916 us; speedup vs baseline: 5.2778x; 1.1819x over previous
//
#include <hip/hip_runtime.h>
#include <hip/hip_cooperative_groups.h>

// Persistent cooperative LSTM kernel.
// Grid = 256 WGs x 128 threads. WG id decode (static, R3-proven):
//   layer = wg>>7, dir = (wg>>6)&1, colblk = (wg>>1)&31 (8 h-cols), mhalf = wg&1 (32 batch rows)
// R1: cg grid.sync (~32us/step) -> hand barrier+fences: 24us/step.
// R2: removed cache maintenance; coherent sc0sc1 IC data path: 7.3us/step.
// R3: global barrier -> 8 decoupled group chains, IC counters: 6.7us/step.
//     Residual cost diagnosed: 32 serialized atomic RMWs on one counter line per step.
// R4: XCD-claiming attempt FAILED (infra fault; workspace overflow suspected). Reverted.
// R5: NO RMWs. Per-WG monotonic flag words (own 32B slot, plain SYSTEM store) +
//     wave-parallel 64-flag polling (one IC RTT per poll iteration, __all reduce).

typedef short v8s __attribute__((ext_vector_type(8)));
typedef float v4f __attribute__((ext_vector_type(4)));
typedef unsigned long long u64;

#define S_LEN 512
#define BATCH 64
#define EMBD  300
#define XPAD  320
#define ROWP0 584   // 320 (x, padded) + 256 (h) + 8 pad
#define ROWP1 776   // 512 (x1) + 256 (h) + 8 pad
#define NWG   256

__device__ inline unsigned short f2bf(float x) {
  union { float f; unsigned u; } v; v.f = x;
  unsigned r = v.u + 0x7FFF + ((v.u >> 16) & 1);   // RNE
  return (unsigned short)(r >> 16);
}
__device__ inline float sigm(float x) { return 1.f / (1.f + __expf(-x)); }
__device__ inline float tanhf_(float x) {
  float e = __expf(-2.f * fabsf(x));
  float r = (1.f - e) / (1.f + e);
  return x >= 0.f ? r : -r;
}

// IC-coherent (sc0 sc1) accessors — R2/R3-proven SYSTEM scope.
__device__ inline v8s ld_sys16(const unsigned short* p) {
  union { u64 q[2]; v8s s; } u;
  u.q[0] = __hip_atomic_load((const u64*)p,     __ATOMIC_RELAXED, __HIP_MEMORY_SCOPE_SYSTEM);
  u.q[1] = __hip_atomic_load((const u64*)p + 1, __ATOMIC_RELAXED, __HIP_MEMORY_SCOPE_SYSTEM);
  return u.s;
}
__device__ inline float ldf_sys(const float* p) {
  return __hip_atomic_load(p, __ATOMIC_RELAXED, __HIP_MEMORY_SCOPE_SYSTEM);
}
__device__ inline unsigned ldu_sys(const unsigned* p) {
  return __hip_atomic_load(p, __ATOMIC_RELAXED, __HIP_MEMORY_SCOPE_SYSTEM);
}
__device__ inline void st4_sys(unsigned* p, unsigned v) {
  __hip_atomic_store(p, v, __ATOMIC_RELAXED, __HIP_MEMORY_SCOPE_SYSTEM);
}
__device__ inline void stf_sys(float* p, float v) {
  __hip_atomic_store(p, v, __ATOMIC_RELAXED, __HIP_MEMORY_SCOPE_SYSTEM);
}

// Wave-parallel flag poll: each lane checks (pollp ? *pollp >= thr : true); loop
// until all 64 lanes satisfied. One IC round trip checks up to 64 flags.
__device__ inline void wave_poll(const unsigned* pollp, unsigned thr) {
  if (__all((pollp == nullptr) || (thr == 0u)) ) return;
  for (;;) {
    bool ok = (pollp == nullptr) || (thr == 0u) || (ldu_sys(pollp) >= thr);
    if (__all(ok)) break;
    __builtin_amdgcn_s_sleep(1);
  }
}

template<int NKA, int NKB, int P2OFF>
__device__ inline void mfma_dual(const v8s* a, const unsigned short* t0,
                                 const unsigned short* t1, v4f& acc0, v4f& acc1) {
#pragma unroll
  for (int i = 0; i < NKA; ++i) {
    v8s b0 = *(const v8s*)(t0 + i * 32);
    v8s b1 = *(const v8s*)(t1 + i * 32);
    acc0 = __builtin_amdgcn_mfma_f32_16x16x32_bf16(a[i], b0, acc0, 0, 0, 0);
    acc1 = __builtin_amdgcn_mfma_f32_16x16x32_bf16(a[i], b1, acc1, 0, 0, 0);
  }
#pragma unroll
  for (int i = 0; i < NKB; ++i) {
    v8s b0 = *(const v8s*)(t0 + P2OFF + i * 32);
    v8s b1 = *(const v8s*)(t1 + P2OFF + i * 32);
    acc0 = __builtin_amdgcn_mfma_f32_16x16x32_bf16(a[NKA + i], b0, acc0, 0, 0, 0);
    acc1 = __builtin_amdgcn_mfma_f32_16x16x32_bf16(a[NKA + i], b1, acc1, 0, 0, 0);
  }
}

__global__ void __launch_bounds__(128, 1)
ContextAwareModel_9655086481739_kernel(
    const int* __restrict__ contexts, const int* __restrict__ positions,
    const float* __restrict__ emb,
    const float* __restrict__ wih0, const float* __restrict__ whh0,
    const float* __restrict__ bih0, const float* __restrict__ bhh0,
    const float* __restrict__ wih1, const float* __restrict__ whh1,
    const float* __restrict__ bih1, const float* __restrict__ bhh1,
    const float* __restrict__ wcls, const float* __restrict__ bcls,
    float* __restrict__ out, unsigned char* __restrict__ ws)
{
  __shared__ unsigned short smem[32 * ROWP1];   // 49,664 B

  const int wg   = blockIdx.x;
  const int tid  = threadIdx.x;
  const int layer  = wg >> 7;
  const int d      = (wg >> 6) & 1;
  const int colblk = (wg >> 1) & 31;
  const int mhalf  = wg & 1;
  const int wv   = tid >> 6;
  const int lane = tid & 63;
  const int quad = lane >> 4;
  const int lc   = lane & 15;
  const int hc0  = colblk * 8;
  const int hc   = hc0 + (lc & 7);
  const int m0   = mhalf * 32 + wv * 16;
  const int r_base = m0 + quad * 4;
  const int gid  = layer * 4 + d * 2 + mhalf;

  // workspace layout (bytes) — identical to R3 (proven to fit ws_size):
  //   Xbuf[512][64][320] bf16          @ 0         (20,971,520)
  //   h0  [4][64][512]  bf16 (ring 4)  @ 20971520  (262,144)
  //   h1  [2][2][64][256] bf16         @ 21233664  (131,072)
  //   tgt [64][512] f32                @ 21364736  (131,072)
  //   flags[8][32] u32, 32B stride     @ 21495808  (8,192)  -> top 21,504,000
  unsigned short* Xbuf  = (unsigned short*)ws;
  unsigned short* h0buf = (unsigned short*)(ws + 20971520u);
  unsigned short* h1buf = (unsigned short*)(ws + 20971520u + 262144u);
  float*          tgt   = (float*)(ws + 20971520u + 262144u + 131072u);
  unsigned*       flags = (unsigned*)(ws + 20971520u + 262144u + 131072u + 131072u);
  // flag slot (g, s) at flags[(g*32+s)*8]  (32 B / slot; monotonic step counter)

  const int ROWP = layer ? ROWP1 : ROWP0;

  // ---------------- stage 0 ----------------
  { // zero h-state (h0 4 parities + h1 2 parities = 393216 B = 196608 shorts)
    for (int i = wg * 128 + tid; i < 196608; i += NWG * 128) h0buf[i] = 0;
    if (wg == 0) { for (int i = tid; i < 2048; i += 128) flags[i] = 0; }
  }
  { // embedding gather -> bf16, padded to 320
    int gw2 = wg * 2 + wv;                     // 0..511 waves
    for (int rl = 0; rl < 64; ++rl) {
      int rr = gw2 * 64 + rl;                  // rr = t*64 + b
      int t = rr >> 6, b = rr & 63;
      int tok = contexts[b * S_LEN + t];
      const float* erow = emb + (long)tok * EMBD;
#pragma unroll
      for (int i = 0; i < 5; ++i) {
        int kk = i * 64 + lane;
        float v = (kk < EMBD) ? erow[kk] : 0.f;
        if (kk < XPAD) Xbuf[rr * XPAD + kk] = f2bf(v);
      }
    }
  }
  { // weights -> LDS (bf16). Row lr: tile T=lr>>4, col c=lr&15, gate = T*2+(c>>3)
    const float* wih = layer ? wih1 : wih0;
    const float* whh = layer ? whh1 : whh0;
    const int KI  = layer ? 512 : 300;
    const int KIp = layer ? 512 : 320;
    const int KT  = layer ? 768 : 576;
    int lr = tid >> 2, sub = tid & 3;
    int c = lr & 15, T = lr >> 4;
    int gate = T * 2 + (c >> 3);
    int j = gate * 256 + hc0 + (c & 7);
    const float* wri = wih + (long)(d * 1024 + j) * KI;
    const float* wrh = whh + (long)(d * 1024 + j) * 256;
    for (int kk = sub; kk < ROWP; kk += 4) {
      float v = 0.f;
      if (kk < KI) v = wri[kk];
      else if (kk >= KIp && kk < KT) v = wrh[kk - KIp];
      smem[lr * ROWP + kk] = f2bf(v);
    }
  }
  float bias0, bias1;
  {
    const float* bi = layer ? bih1 : bih0;
    const float* bh = layer ? bhh1 : bhh0;
    int j0 = ((lc >> 3) & 1) * 256 + hc;        // gate i/f
    int j1 = (2 + ((lc >> 3) & 1)) * 256 + hc;  // gate g/o
    bias0 = bi[d * 1024 + j0] + bh[d * 1024 + j0];
    bias1 = bi[d * 1024 + j1] + bh[d * 1024 + j1];
  }
  int pos[4];
#pragma unroll
  for (int j = 0; j < 4; ++j) pos[j] = positions[r_base + j];
  float cst[4] = {0.f, 0.f, 0.f, 0.f};
  const unsigned short* lds_t0 = smem + lc * ROWP + quad * 8;
  const unsigned short* lds_t1 = smem + (16 + lc) * ROWP + quad * 8;
  const bool hi = (lc & 8) != 0;

  // Per-lane poll assignment (fixed across the t-loop):
  //   cls 0 = own group (thr = t), cls 1 = cross group (layer0: thr = max(t-3,0)
  //   back-pressure on layer1; layer1: thr = t+1 on layer0), cls -1 = idle.
  const unsigned* pollp = nullptr;
  int pollcls = -1;
  if (layer == 0) {
    if (wv == 0) {
      if (lane < 32) { pollp = flags + (gid * 32 + lane) * 8;            pollcls = 0; }
      else           { pollp = flags + ((4 + mhalf) * 32 + lane - 32) * 8; pollcls = 1; }
    } else {
      if (lane < 32) { pollp = flags + ((6 + mhalf) * 32 + lane) * 8;     pollcls = 1; }
    }
  } else {
    if (wv == 0) {
      if (lane < 32) { pollp = flags + (gid * 32 + lane) * 8;            pollcls = 0; }
      else           { pollp = flags + ((0 + mhalf) * 32 + lane - 32) * 8; pollcls = 1; }
    } else {
      if (lane < 32) { pollp = flags + ((2 + mhalf) * 32 + lane) * 8;     pollcls = 1; }
    }
  }
  unsigned* myflag = flags + (gid * 32 + colblk) * 8;

  // one known-correct cooperative sync: publishes Xbuf, zeroed h-state, zeroed flags
  cooperative_groups::grid_group gg = cooperative_groups::this_grid();
  __syncthreads();
  gg.sync();

  // ---------------- recurrence: flag-paced pipelines ----------------
  if (layer == 0) {
    for (int t = 0; t < S_LEN; ++t) {
      v8s a[18];
      { // X fragments are wait-independent: prefetch before polling
        const unsigned short* aP1 = Xbuf + (t * BATCH + m0 + lc) * XPAD + quad * 8;
#pragma unroll
        for (int i = 0; i < 10; ++i) a[i] = *(const v8s*)(aP1 + i * 32);
      }
      {
        unsigned thr = 0;
        if (pollcls == 0) thr = (unsigned)t;
        else if (pollcls == 1) thr = (t >= 4) ? (unsigned)(t - 3) : 0u;
        wave_poll(pollp, thr);
      }
      __syncthreads();
      { // h0_{t-1} (ring slot (t-1)&3), own dir half
        const unsigned short* aP2 = h0buf + ((t + 3) & 3) * 32768 + (m0 + lc) * 512 + d * 256 + quad * 8;
#pragma unroll
        for (int i = 0; i < 8; ++i) a[10 + i] = ld_sys16(aP2 + i * 32);
      }
      v4f acc0 = {bias0, bias0, bias0, bias0};
      v4f acc1 = {bias1, bias1, bias1, bias1};
      mfma_dual<10, 8, 320>(a, lds_t0, lds_t1, acc0, acc1);
#pragma unroll
      for (int j = 0; j < 4; ++j) {
        float a0 = acc0[j], a1 = acc1[j];
        float o0 = __shfl_xor(a0, 8);
        float o1 = __shfl_xor(a1, 8);
        float iv = hi ? o0 : a0;
        float fv = hi ? a0 : o0;
        float gv = hi ? o1 : a1;
        float ov = hi ? a1 : o1;
        float ii = sigm(iv), ff = sigm(fv), ggt = tanhf_(gv), oo = sigm(ov);
        float cn = ff * cst[j] + ii * ggt;
        cst[j] = cn;
        float hv = oo * tanhf_(cn);
        unsigned hb = f2bf(hv);
        unsigned ob = ((unsigned)__shfl_xor((int)hb, 1)) & 0xFFFFu;
        if (lc < 8 && !(lc & 1)) {
          unsigned word = hb | (ob << 16);
          st4_sys((unsigned*)&h0buf[(t & 3) * 32768 + (r_base + j) * 512 + d * 256 + hc], word);
        }
      }
      asm volatile("s_waitcnt vmcnt(0)" ::: "memory");
      __syncthreads();
      if (tid == 0) st4_sys(myflag, (unsigned)(t + 1));
    }
  } else {
    for (int t = 0; t < S_LEN; ++t) {
      {
        unsigned thr = (pollcls == 0) ? (unsigned)t
                     : (pollcls == 1) ? (unsigned)(t + 1) : 0u;
        wave_poll(pollp, thr);
      }
      __syncthreads();
      v8s a[24];
      { // h0_t (both dirs) — produced this step by layer0
        const unsigned short* p = h0buf + (t & 3) * 32768 + (m0 + lc) * 512 + quad * 8;
#pragma unroll
        for (int i = 0; i < 16; ++i) a[i] = ld_sys16(p + i * 32);
      }
      { // h1_{t-1}, own dir half
        const unsigned short* p = h1buf + ((t + 1) & 1) * 32768 + d * 16384 + (m0 + lc) * 256 + quad * 8;
#pragma unroll
        for (int i = 0; i < 8; ++i) a[16 + i] = ld_sys16(p + i * 32);
      }
      v4f acc0 = {bias0, bias0, bias0, bias0};
      v4f acc1 = {bias1, bias1, bias1, bias1};
      mfma_dual<16, 8, 512>(a, lds_t0, lds_t1, acc0, acc1);
#pragma unroll
      for (int j = 0; j < 4; ++j) {
        float a0 = acc0[j], a1 = acc1[j];
        float o0 = __shfl_xor(a0, 8);
        float o1 = __shfl_xor(a1, 8);
        float iv = hi ? o0 : a0;
        float fv = hi ? a0 : o0;
        float gv = hi ? o1 : a1;
        float ov = hi ? a1 : o1;
        float ii = sigm(iv), ff = sigm(fv), ggt = tanhf_(gv), oo = sigm(ov);
        float cn = ff * cst[j] + ii * ggt;
        cst[j] = cn;
        float hv = oo * tanhf_(cn);
        unsigned hb = f2bf(hv);
        unsigned ob = ((unsigned)__shfl_xor((int)hb, 1)) & 0xFFFFu;
        int r = r_base + j;
        if (lc < 8 && !(lc & 1)) {
          unsigned word = hb | (ob << 16);
          st4_sys((unsigned*)&h1buf[(t & 1) * 32768 + d * 16384 + r * 256 + hc], word);
        }
        if (lc < 8 && pos[j] == t) stf_sys(&tgt[r * 512 + d * 256 + hc], hv);
      }
      asm volatile("s_waitcnt vmcnt(0)" ::: "memory");
      __syncthreads();
      if (tid == 0) st4_sys(myflag, (unsigned)(t + 1));
    }
  }

  // final join: all layer-1 groups at S_LEN -> tgt complete
  {
    int g = (wv == 0) ? 4 : 6;
    const unsigned* jp = flags + ((g + (lane >> 5)) * 32 + (lane & 31)) * 8;
    wave_poll(jp, (unsigned)S_LEN);
  }
  __syncthreads();

  // ---------------- epilogue ----------------
  {
    for (int i = wg * 128 + tid; i < BATCH * 512; i += NWG * 128) out[256 + i] = ldf_sys(&tgt[i]);
    int gw = wg * 2 + wv;
    if (gw < 128) {                 // one wave per (b, class)
      int b = gw >> 1, cl2 = gw & 1;
      float s = 0.f;
#pragma unroll
      for (int i = 0; i < 8; ++i) {
        int j = i * 64 + lane;
        s += ldf_sys(&tgt[b * 512 + j]) * wcls[cl2 * 512 + j];
      }
      s += __shfl_xor(s, 32); s += __shfl_xor(s, 16); s += __shfl_xor(s, 8);
      s += __shfl_xor(s, 4);  s += __shfl_xor(s, 2);  s += __shfl_xor(s, 1);
      if (lane == 0) {
        float L = s + bcls[cl2];
        out[b * 2 + cl2] = L;             // logits
        out[128 + b * 2 + cl2] = sigm(L); // probs
      }
    }
  }
}

extern "C" void kernel_launch(void* const* d_in, const int* in_sizes, int n_in,
                              void* d_out, int out_size, void* d_ws, size_t ws_size,
                              hipStream_t stream) {
  (void)in_sizes; (void)n_in; (void)out_size; (void)ws_size;
  const int*   contexts  = (const int*)d_in[0];
  const int*   positions = (const int*)d_in[1];
  const float* emb   = (const float*)d_in[2];
  const float* wih0  = (const float*)d_in[3];
  const float* whh0  = (const float*)d_in[4];
  const float* bih0  = (const float*)d_in[5];
  const float* bhh0  = (const float*)d_in[6];
  const float* wih1  = (const float*)d_in[7];
  const float* whh1  = (const float*)d_in[8];
  const float* bih1  = (const float*)d_in[9];
  const float* bhh1  = (const float*)d_in[10];
  const float* wcls  = (const float*)d_in[11];
  const float* bcls  = (const float*)d_in[12];
  float* out = (float*)d_out;
  unsigned char* ws = (unsigned char*)d_ws;

  void* args[] = { &contexts, &positions, &emb,
                   &wih0, &whh0, &bih0, &bhh0,
                   &wih1, &whh1, &bih1, &bhh1,
                   &wcls, &bcls, &out, &ws };
  hipLaunchCooperativeKernel((const void*)ContextAwareModel_9655086481739_kernel,
                             dim3(NWG), dim3(128), args, 0, stream);
}